// Round 13
// baseline (403.165 us; speedup 1.0000x reference)
//
#include <hip/hip_runtime.h>
#include <hip/hip_bf16.h>

#define Bdim 256
#define Ddim 1024
#define Hdim 2048
#define Tdim 100
#define BH (Bdim*Hdim)            // 524288
#define M3 ((Tdim-1)*Bdim)        // 25344
#define ZB8 ((size_t)M3*Hdim)     // i8 Z bytes = 51,904,512

#define OUT_MEM ((size_t)BH)                          // mem_rec starts after out0
#define OUT_SPK ((size_t)BH + (size_t)Tdim*2*BH)      // spk_rec after mem_rec

typedef __attribute__((ext_vector_type(8))) short short8;
typedef __attribute__((ext_vector_type(4))) float f32x4;
typedef __attribute__((ext_vector_type(4))) int   i32x4;

// async global->LDS, 16B per lane, LDS dest = wave-uniform base + lane*16
#define GLD16(g, l) __builtin_amdgcn_global_load_lds( \
    (__attribute__((address_space(1))) void*)(g), \
    (__attribute__((address_space(3))) void*)(l), 16, 0, 0)

static __device__ __forceinline__ unsigned short bf16bits(float f) {
  __hip_bfloat16 h = __float2bfloat16(f);
  return *reinterpret_cast<unsigned short*>(&h);
}

// ---------------- kcvt_split: X f32 -> bf16 hi + bf16 lo(residual) ----------------
__global__ __launch_bounds__(256) void kcvt_split(const float* __restrict__ X,
                                                  unsigned short* __restrict__ Xhi,
                                                  unsigned short* __restrict__ Xlo) {
  int i = (blockIdx.x*256 + threadIdx.x)*4;
  float4 v = *reinterpret_cast<const float4*>(&X[i]);
  ushort4 ph, pl;
  float f, fh;
  f = v.x; { __hip_bfloat16 h = __float2bfloat16(f); fh = __bfloat162float(h); ph.x = *reinterpret_cast<unsigned short*>(&h); } pl.x = bf16bits(f - fh);
  f = v.y; { __hip_bfloat16 h = __float2bfloat16(f); fh = __bfloat162float(h); ph.y = *reinterpret_cast<unsigned short*>(&h); } pl.y = bf16bits(f - fh);
  f = v.z; { __hip_bfloat16 h = __float2bfloat16(f); fh = __bfloat162float(h); ph.z = *reinterpret_cast<unsigned short*>(&h); } pl.z = bf16bits(f - fh);
  f = v.w; { __hip_bfloat16 h = __float2bfloat16(f); fh = __bfloat162float(h); ph.w = *reinterpret_cast<unsigned short*>(&h); } pl.w = bf16bits(f - fh);
  *reinterpret_cast<ushort4*>(&Xhi[i]) = ph;
  *reinterpret_cast<ushort4*>(&Xlo[i]) = pl;
}

// ---------------- ktr_split: transposed hi/lo split of In (f32) ----------------
__global__ __launch_bounds__(256) void ktr_split(const float* __restrict__ In,
                                                 unsigned short* __restrict__ OutHi,
                                                 unsigned short* __restrict__ OutLo,
                                                 int R, int C) {
  __shared__ unsigned short thi[32][33];
  __shared__ unsigned short tlo[32][33];
  int bk = blockIdx.x*32, bn = blockIdx.y*32;
  int tx = threadIdx.x & 31, ty = threadIdx.x >> 5;
  for (int r = ty; r < 32; r += 8) {
    float f = In[(size_t)(bk + r)*C + bn + tx];
    __hip_bfloat16 h = __float2bfloat16(f);
    float fh = __bfloat162float(h);
    thi[r][tx] = *reinterpret_cast<unsigned short*>(&h);
    tlo[r][tx] = bf16bits(f - fh);
  }
  __syncthreads();
  for (int r = ty; r < 32; r += 8) {
    OutHi[(size_t)(bn + r)*R + bk + tx] = thi[tx][r];
    OutLo[(size_t)(bn + r)*R + bk + tx] = tlo[tx][r];
  }
}

// ---------------- kcolmax 2-stage (validated r12; bit-identical scales) ----------------
__global__ __launch_bounds__(256) void kcolmax_part(const float* __restrict__ W1,
                                                    float* __restrict__ pmax) {
  int n = blockIdx.x*256 + threadIdx.x;
  int kc = blockIdx.y;
  float m = 0.f;
  #pragma unroll 8
  for (int k = kc*64; k < kc*64 + 64; ++k)
    m = fmaxf(m, fabsf(W1[(size_t)k*Hdim + n]));
  pmax[(size_t)kc*Hdim + n] = m;
}

__global__ __launch_bounds__(256) void kcolmax_fin(const float* __restrict__ pmax,
                                                   float* __restrict__ scales) {
  int n = blockIdx.x*256 + threadIdx.x;
  float m = 0.f;
  #pragma unroll
  for (int i = 0; i < 32; ++i)
    m = fmaxf(m, pmax[(size_t)i*Hdim + n]);
  scales[n] = m * (1.0f/127.0f);
}

// ---------------- ktr_i8: W1T8[n][k] = rint(W1[k][n]/scales[n]) ----------------
__global__ __launch_bounds__(256) void ktr_i8(const float* __restrict__ In,
                                              const float* __restrict__ scales,
                                              signed char* __restrict__ Out) {
  __shared__ signed char tile[32][33];
  int bk = blockIdx.x*32, bn = blockIdx.y*32;
  int tx = threadIdx.x & 31, ty = threadIdx.x >> 5;
  float rs = 1.0f / scales[bn + tx];      // column n = bn+tx
  for (int r = ty; r < 32; r += 8)
    tile[r][tx] = (signed char)(int)rintf(In[(size_t)(bk + r)*Hdim + bn + tx] * rs);
  __syncthreads();
  for (int r = ty; r < 32; r += 8)
    Out[(size_t)(bn + r)*Hdim + bk + tx] = tile[tx][r];
}

// ---------------- K1 fused: ns0 = xhi@whiT + xhi@wloT + xlo@whiT (validated r8) ----------------
#define K1F_NK 32   // K = 1024, BK = 32
__global__ __launch_bounds__(256) void k1_fused(const unsigned short* __restrict__ xhi,
                                                const unsigned short* __restrict__ xlo,
                                                const unsigned short* __restrict__ whiT,
                                                const unsigned short* __restrict__ wloT,
                                                float* __restrict__ NS0) {
  __shared__ short Ah[2][64*32], Al[2][64*32];
  __shared__ short Bh[2][64*32], Bl[2][64*32];
  int tid = threadIdx.x;
  int l = tid & 63, w = tid >> 6;
  int wm = w >> 1, wn = w & 1;
  int lr = l & 15, lg = l >> 4;
  size_t gm = (size_t)blockIdx.x * 64;
  size_t gn = (size_t)blockIdx.y * 64;
  int srow = l >> 2;
  int scol = ((l & 3)*8) ^ (((l >> 2) & 6) << 2);
  const unsigned short* gah = &xhi [(gm + w*16 + srow)*1024 + scol];
  const unsigned short* gal = &xlo [(gm + w*16 + srow)*1024 + scol];
  const unsigned short* gbh = &whiT[(gn + w*16 + srow)*1024 + scol];
  const unsigned short* gbl = &wloT[(gn + w*16 + srow)*1024 + scol];
  int rdswz = (lr & 6) << 2;
  f32x4 acc[2][2] = {};
  GLD16(gah, &Ah[0][w*512]); GLD16(gal, &Al[0][w*512]);
  GLD16(gbh, &Bh[0][w*512]); GLD16(gbl, &Bl[0][w*512]);
  __syncthreads();
  #pragma unroll 2
  for (int t = 0; t < K1F_NK; ++t) {
    int cur = t & 1;
    if (t + 1 < K1F_NK) {
      int nxt = cur ^ 1; size_t ko = (size_t)(t + 1)*32;
      GLD16(gah + ko, &Ah[nxt][w*512]); GLD16(gal + ko, &Al[nxt][w*512]);
      GLD16(gbh + ko, &Bh[nxt][w*512]); GLD16(gbl + ko, &Bl[nxt][w*512]);
    }
    short8 ah[2], al[2], bh[2], bl[2];
    #pragma unroll
    for (int mi = 0; mi < 2; ++mi) {
      int ro = (wm*32 + mi*16 + lr)*32 + (lg*8 ^ rdswz);
      ah[mi] = *reinterpret_cast<const short8*>(&Ah[cur][ro]);
      al[mi] = *reinterpret_cast<const short8*>(&Al[cur][ro]);
    }
    #pragma unroll
    for (int ni = 0; ni < 2; ++ni) {
      int ro = (wn*32 + ni*16 + lr)*32 + (lg*8 ^ rdswz);
      bh[ni] = *reinterpret_cast<const short8*>(&Bh[cur][ro]);
      bl[ni] = *reinterpret_cast<const short8*>(&Bl[cur][ro]);
    }
    #pragma unroll
    for (int mi = 0; mi < 2; ++mi)
      #pragma unroll
      for (int ni = 0; ni < 2; ++ni) {
        acc[mi][ni] = __builtin_amdgcn_mfma_f32_16x16x32_bf16(ah[mi], bh[ni], acc[mi][ni], 0, 0, 0);
        acc[mi][ni] = __builtin_amdgcn_mfma_f32_16x16x32_bf16(ah[mi], bl[ni], acc[mi][ni], 0, 0, 0);
        acc[mi][ni] = __builtin_amdgcn_mfma_f32_16x16x32_bf16(al[mi], bh[ni], acc[mi][ni], 0, 0, 0);
      }
    __syncthreads();
  }
  #pragma unroll
  for (int mi = 0; mi < 2; ++mi)
    #pragma unroll
    for (int ni = 0; ni < 2; ++ni)
      #pragma unroll
      for (int q = 0; q < 4; ++q)
        NS0[(gm + wm*32 + mi*16 + lg*4 + q)*Hdim + gn + wn*32 + ni*16 + lr] = acc[mi][ni][q];
}

// ---------------- K2: layer-0 sim (x4 vectorized); writes mem0, spk, zeros, i8 Z ----------------
__global__ __launch_bounds__(256) void k2_sim(const float* __restrict__ NS0,
                                              float* __restrict__ out,
                                              signed char* __restrict__ Zb) {
  size_t i4 = ((size_t)blockIdx.x*256 + threadIdx.x)*4;
  float4 nsv = *reinterpret_cast<const float4*>(&NS0[i4]);
  float ns[4] = {nsv.x, nsv.y, nsv.z, nsv.w};
  float* mem = out + OUT_MEM;
  float* spk = out + OUT_SPK;
  float4 z4 = {0.f, 0.f, 0.f, 0.f};
  *reinterpret_cast<float4*>(&mem[i4]) = z4;
  *reinterpret_cast<float4*>(&mem[BH + i4]) = z4;
  *reinterpret_cast<float4*>(&spk[i4]) = z4;
  float m[4] = {0.f, 0.f, 0.f, 0.f};
  for (int t = 1; t < Tdim; ++t) {
    float4 mo, zf; uchar4 z8;
    #pragma unroll
    for (int j = 0; j < 4; ++j) {
      m[j] = __fadd_rn(__fmul_rn(0.9f, m[j]), ns[j]);
      bool sp = m[j] > 1.0f;
      if (sp) m[j] = 0.f;
      ((float*)&mo)[j] = m[j];
      ((float*)&zf)[j] = sp ? 1.f : 0.f;
      ((unsigned char*)&z8)[j] = sp ? (unsigned char)1 : (unsigned char)0;  // i8 1/0
    }
    *reinterpret_cast<float4*>(&mem[(size_t)(2*t)*BH + i4]) = mo;
    *reinterpret_cast<float4*>(&spk[(size_t)t*BH + i4]) = zf;
    *reinterpret_cast<uchar4*>(&Zb[(size_t)(t-1)*BH + i4]) = z8;
  }
}

// ---------------- K3: C = (Z @ W1q) * scale_n, i8 MFMA K=64, 256^2 tile, BK=64 ----
// r12 ran 6 barriers/K-tile; with i8's short phases that was barrier-bound
// (~190us vs ~50us LDS/MFMA arithmetic). New: T3-minimum schedule — stage the
// ENTIRE next tile into buf^1 at body start (zero intra-tile WAR hazards: buf^1's
// old data fully read in tile kt-1, proven by the kt-entry barrier), then all
// reads+MFMAs compiler-scheduled, then ONE vmcnt(0)+barrier at body end.
#define NKT3 32   // 2048/64

#define K3_ST(g, ldsarr, half, kt) \
  GLD16((g) + (size_t)(kt)*64 + (size_t)(half)*128*2048, &ldsarr[(kt)&1][(half)*8192 + w*1024])

// row byte-length 64 = 4 chunks of 16B; lane (lr,lg) reads chunk (lg ^ rxa), k-slice lg*16..+15
#define K3_LDA(h) do { \
  _Pragma("unroll") \
  for (int mi = 0; mi < 4; ++mi) \
    af[mi] = *reinterpret_cast<const i32x4*>( \
      &As[bb][((h)*128 + wm*64 + mi*16 + lr)*64 + ((lg ^ rxa)<<4)]); \
} while(0)

#define K3_LDB(v, bf) do { \
  _Pragma("unroll") \
  for (int ni = 0; ni < 2; ++ni) \
    bf[ni] = *reinterpret_cast<const i32x4*>( \
      &Bs[bb][((v)*128 + wn*32 + ni*16 + lr)*64 + ((lg ^ rxa)<<4)]); \
} while(0)

#define K3_MFMA(h, v, bf) do { \
  __builtin_amdgcn_s_setprio(1); \
  _Pragma("unroll") \
  for (int mi = 0; mi < 4; ++mi) \
    _Pragma("unroll") \
    for (int ni = 0; ni < 2; ++ni) \
      acc[(h)*4+mi][(v)*2+ni] = __builtin_amdgcn_mfma_i32_16x16x64_i8(af[mi], bf[ni], acc[(h)*4+mi][(v)*2+ni], 0, 0, 0); \
  __builtin_amdgcn_s_setprio(0); \
} while(0)

template<int CB>
__global__ __launch_bounds__(512, 2) void k3_gemm(const signed char* __restrict__ A,    // Zb i8 [M3][2048]
                                                  const signed char* __restrict__ BT,   // W1T8 [2048][2048]
                                                  const float* __restrict__ scales,     // [2048] colmax/127
                                                  float* __restrict__ mem1,
                                                  unsigned short* __restrict__ cbuf) {
  __shared__ signed char As[2][256*64];   // 16 KB x2
  __shared__ signed char Bs[2][256*64];   // 16 KB x2  (64 KB total -> 2 blocks/CU)
  int tid = threadIdx.x;
  int l = tid & 63;
  int w = tid >> 6;                 // wave 0..7
  int wm = w >> 2, wn = w & 3;      // 2M x 4N; per-wave out 128x64
  int lr = l & 15, lg = l >> 4;
  int rxa = (lr >> 1) & 3;          // read-side chunk XOR == (R>>1)&3 for all our rows

  // T1: grid 792 = 8*99 bijective, ntile fast
  int lin = blockIdx.x;
  int wg = (lin & 7)*99 + (lin >> 3);
  int mtile = wg >> 3, ntile = wg & 7;
  size_t gm = (size_t)mtile * 256;
  size_t gn = (size_t)ntile * 256;

  // staging: lane l covers row l>>2, 16B chunk l&3, source chunk pre-XOR (l>>3)&3
  int srow = l >> 2;
  int scol = ((l & 3) ^ ((l >> 3) & 3)) << 4;
  const signed char* gA = &A [(gm + w*16 + srow)*2048 + scol];
  const signed char* gB = &BT[(gn + w*16 + srow)*2048 + scol];

  i32x4 acc[8][4] = {};

  // prologue: stage tile 0 into buf0, drain, sync
  K3_ST(gA, As, 0, 0); K3_ST(gA, As, 1, 0);
  K3_ST(gB, Bs, 0, 0); K3_ST(gB, Bs, 1, 0);
  asm volatile("s_waitcnt vmcnt(0)" ::: "memory");
  __builtin_amdgcn_s_barrier();
  asm volatile("" ::: "memory");

  for (int kt = 0; kt < NKT3; ++kt) {
    int bb = kt & 1;
    // invariant at entry: buf[bb] holds tile kt (drained), all waves synced.
    // stage tile kt+1 into buf[bb^1] (its old contents fully read in kt-1).
    if (kt + 1 < NKT3) {
      K3_ST(gA, As, 0, kt + 1); K3_ST(gA, As, 1, kt + 1);
      K3_ST(gB, Bs, 0, kt + 1); K3_ST(gB, Bs, 1, kt + 1);
    }
    i32x4 af[4], bfl[2], bfh[2];
    K3_LDA(0); K3_LDB(0, bfl); K3_LDB(1, bfh);
    K3_MFMA(0, 0, bfl);
    K3_MFMA(0, 1, bfh);
    K3_LDA(1);
    K3_MFMA(1, 0, bfl);
    K3_MFMA(1, 1, bfh);
    // end of tile: kt+1's loads landed (issued ~whole body ago) + all waves done with bb
    asm volatile("s_waitcnt vmcnt(0)" ::: "memory");
    __builtin_amdgcn_s_barrier();
    asm volatile("" ::: "memory");
  }

  // epilogue: dequant by per-column scale; M-tile == C plane t = mtile+1
  float sc[2][2];
  #pragma unroll
  for (int vv = 0; vv < 2; ++vv)
    #pragma unroll
    for (int ni = 0; ni < 2; ++ni)
      sc[vv][ni] = scales[gn + vv*128 + wn*32 + ni*16 + lr];

  if (CB) {
    unsigned short* cp = cbuf + (size_t)mtile*BH + gn;
    #pragma unroll
    for (int hh = 0; hh < 2; ++hh)
      #pragma unroll
      for (int mi = 0; mi < 4; ++mi)
        #pragma unroll
        for (int vv = 0; vv < 2; ++vv)
          #pragma unroll
          for (int ni = 0; ni < 2; ++ni)
            #pragma unroll
            for (int q = 0; q < 4; ++q) {
              int b   = hh*128 + wm*64 + mi*16 + lg*4 + q;
              int col = vv*128 + wn*32 + ni*16 + lr;
              cp[(size_t)b*Hdim + col] =
                bf16bits((float)acc[hh*4+mi][vv*2+ni][q] * sc[vv][ni]);
            }
  } else {
    float* plane = mem1 + (size_t)(2*mtile + 3)*BH + gn;
    #pragma unroll
    for (int hh = 0; hh < 2; ++hh)
      #pragma unroll
      for (int mi = 0; mi < 4; ++mi)
        #pragma unroll
        for (int vv = 0; vv < 2; ++vv)
          #pragma unroll
          for (int ni = 0; ni < 2; ++ni)
            #pragma unroll
            for (int q = 0; q < 4; ++q) {
              int b   = hh*128 + wm*64 + mi*16 + lg*4 + q;
              int col = vv*128 + wn*32 + ni*16 + lr;
              plane[(size_t)b*Hdim + col] =
                (float)acc[hh*4+mi][vv*2+ni][q] * sc[vv][ni];
            }
  }
}

// ---------------- K4a: in-place recurrence over fp32 C planes (x4 vec) ----------------
__global__ __launch_bounds__(256) void k4_rec(float* __restrict__ out) {
  size_t i4 = ((size_t)blockIdx.x*256 + threadIdx.x)*4;
  float* mem = out + OUT_MEM;
  float s[4] = {0.f,0.f,0.f,0.f}, m[4] = {0.f,0.f,0.f,0.f};
  for (int t = 1; t < Tdim; ++t) {
    float4* p = reinterpret_cast<float4*>(&mem[(size_t)(2*t + 1)*BH + i4]);
    float4 c = *p;
    float4 mo;
    #pragma unroll
    for (int j = 0; j < 4; ++j) {
      s[j] = __fadd_rn(__fmul_rn(0.95f, s[j]), ((float*)&c)[j]);
      m[j] = __fadd_rn(__fmul_rn(0.9f, m[j]), s[j]);
      ((float*)&mo)[j] = m[j];
    }
    *p = mo;
  }
  float4 o = {m[0], m[1], m[2], m[3]};
  *reinterpret_cast<float4*>(&out[i4]) = o;
}

// ---------------- K4b: recurrence reading bf16 cbuf (x4 vec) ----------------
__global__ __launch_bounds__(256) void k4_rec_cb(const unsigned short* __restrict__ C,
                                                 float* __restrict__ out) {
  size_t i4 = ((size_t)blockIdx.x*256 + threadIdx.x)*4;
  float* mem = out + OUT_MEM;
  float s[4] = {0.f,0.f,0.f,0.f}, m[4] = {0.f,0.f,0.f,0.f};
  for (int t = 1; t < Tdim; ++t) {
    ushort4 cv = *reinterpret_cast<const ushort4*>(&C[(size_t)(t-1)*BH + i4]);
    float4 mo;
    #pragma unroll
    for (int j = 0; j < 4; ++j) {
      unsigned int u = ((unsigned short*)&cv)[j];
      float c = __uint_as_float(u << 16);
      s[j] = __fadd_rn(__fmul_rn(0.95f, s[j]), c);
      m[j] = __fadd_rn(__fmul_rn(0.9f, m[j]), s[j]);
      ((float*)&mo)[j] = m[j];
    }
    *reinterpret_cast<float4*>(&mem[(size_t)(2*t + 1)*BH + i4]) = mo;
  }
  float4 o = {m[0], m[1], m[2], m[3]};
  *reinterpret_cast<float4*>(&out[i4]) = o;
}

extern "C" void kernel_launch(void* const* d_in, const int* in_sizes, int n_in,
                              void* d_out, int out_size, void* d_ws, size_t ws_size,
                              hipStream_t stream) {
  const float* X  = (const float*)d_in[0];
  const float* W0 = (const float*)d_in[1];
  const float* W1 = (const float*)d_in[2];
  float* out = (float*)d_out;
  char* ws = (char*)d_ws;

  float*          ns0    = (float*)ws;                                  // 2 MiB @0
  signed char*    w1t8   = (signed char*)(ws + (2ull << 20));           // 4 MiB @2M
  float*          scales = (float*)(ws + (6ull << 20));                 // 8 KiB @6M
  float*          pmax   = (float*)(ws + (6ull << 20) + (64ull << 10)); // 256 KiB @6M+64K
  signed char*    zb     = (signed char*)(ws + (10ull << 20));          // 52 MiB @10M
  unsigned short* cbuf   = (unsigned short*)(ws + (10ull << 20) + ZB8); // 99 MiB, optional
  size_t needCb = (10ull << 20) + ZB8 + (size_t)M3*Hdim*2;
  int useCb = (ws_size >= needCb) ? 1 : 0;
  // hi/lo split inputs overlay the zb region; consumed by k1 before k2 writes Zb
  unsigned short* xhi = (unsigned short*)(ws + (10ull << 20));              // 0.5 MiB
  unsigned short* xlo = (unsigned short*)(ws + (10ull << 20) + (512<<10));  // 0.5 MiB
  unsigned short* whi = (unsigned short*)(ws + (11ull << 20));              // 4 MiB
  unsigned short* wlo = (unsigned short*)(ws + (15ull << 20));              // 4 MiB

  kcvt_split  <<<dim3(256),     256, 0, stream>>>(X, xhi, xlo);
  ktr_split   <<<dim3(32, 64),  256, 0, stream>>>(W0, whi, wlo, 1024, 2048); // W0T hi/lo
  kcolmax_part<<<dim3(8, 32),   256, 0, stream>>>(W1, pmax);
  kcolmax_fin <<<dim3(8),       256, 0, stream>>>(pmax, scales);
  ktr_i8      <<<dim3(64, 64),  256, 0, stream>>>(W1, scales, w1t8);         // W1T8 per-col i8
  k1_fused    <<<dim3(4, 32),   256, 0, stream>>>(xhi, xlo, whi, wlo, ns0);
  k2_sim      <<<dim3(BH/1024), 256, 0, stream>>>(ns0, out, zb);
  if (useCb) {
    k3_gemm<1><<<dim3((M3/256)*(Hdim/256)), 512, 0, stream>>>(zb, w1t8, scales, out + OUT_MEM, cbuf);
    k4_rec_cb<<<dim3(BH/1024), 256, 0, stream>>>(cbuf, out);
  } else {
    k3_gemm<0><<<dim3((M3/256)*(Hdim/256)), 512, 0, stream>>>(zb, w1t8, scales, out + OUT_MEM, cbuf);
    k4_rec  <<<dim3(BH/1024), 256, 0, stream>>>(out);
  }
}

// Round 14
// 359.481 us; speedup vs baseline: 1.1215x; 1.1215x over previous
//
#include <hip/hip_runtime.h>
#include <hip/hip_bf16.h>

#define Bdim 256
#define Ddim 1024
#define Hdim 2048
#define Tdim 100
#define BH (Bdim*Hdim)            // 524288
#define M3 ((Tdim-1)*Bdim)        // 25344
#define ZB8 ((size_t)M3*Hdim)     // i8 Z bytes = 51,904,512

#define OUT_MEM ((size_t)BH)                          // mem_rec starts after out0
#define OUT_SPK ((size_t)BH + (size_t)Tdim*2*BH)      // spk_rec after mem_rec

typedef __attribute__((ext_vector_type(8))) short short8;
typedef __attribute__((ext_vector_type(4))) float f32x4;
typedef __attribute__((ext_vector_type(4))) int   i32x4;

// async global->LDS, 16B per lane, LDS dest = wave-uniform base + lane*16
#define GLD16(g, l) __builtin_amdgcn_global_load_lds( \
    (__attribute__((address_space(1))) void*)(g), \
    (__attribute__((address_space(3))) void*)(l), 16, 0, 0)

static __device__ __forceinline__ unsigned short bf16bits(float f) {
  __hip_bfloat16 h = __float2bfloat16(f);
  return *reinterpret_cast<unsigned short*>(&h);
}

// ---------------- kcvt_split: X f32 -> bf16 hi + bf16 lo(residual) ----------------
__global__ __launch_bounds__(256) void kcvt_split(const float* __restrict__ X,
                                                  unsigned short* __restrict__ Xhi,
                                                  unsigned short* __restrict__ Xlo) {
  int i = (blockIdx.x*256 + threadIdx.x)*4;
  float4 v = *reinterpret_cast<const float4*>(&X[i]);
  ushort4 ph, pl;
  float f, fh;
  f = v.x; { __hip_bfloat16 h = __float2bfloat16(f); fh = __bfloat162float(h); ph.x = *reinterpret_cast<unsigned short*>(&h); } pl.x = bf16bits(f - fh);
  f = v.y; { __hip_bfloat16 h = __float2bfloat16(f); fh = __bfloat162float(h); ph.y = *reinterpret_cast<unsigned short*>(&h); } pl.y = bf16bits(f - fh);
  f = v.z; { __hip_bfloat16 h = __float2bfloat16(f); fh = __bfloat162float(h); ph.z = *reinterpret_cast<unsigned short*>(&h); } pl.z = bf16bits(f - fh);
  f = v.w; { __hip_bfloat16 h = __float2bfloat16(f); fh = __bfloat162float(h); ph.w = *reinterpret_cast<unsigned short*>(&h); } pl.w = bf16bits(f - fh);
  *reinterpret_cast<ushort4*>(&Xhi[i]) = ph;
  *reinterpret_cast<ushort4*>(&Xlo[i]) = pl;
}

// ---------------- ktr_split: transposed hi/lo split of In (f32) ----------------
__global__ __launch_bounds__(256) void ktr_split(const float* __restrict__ In,
                                                 unsigned short* __restrict__ OutHi,
                                                 unsigned short* __restrict__ OutLo,
                                                 int R, int C) {
  __shared__ unsigned short thi[32][33];
  __shared__ unsigned short tlo[32][33];
  int bk = blockIdx.x*32, bn = blockIdx.y*32;
  int tx = threadIdx.x & 31, ty = threadIdx.x >> 5;
  for (int r = ty; r < 32; r += 8) {
    float f = In[(size_t)(bk + r)*C + bn + tx];
    __hip_bfloat16 h = __float2bfloat16(f);
    float fh = __bfloat162float(h);
    thi[r][tx] = *reinterpret_cast<unsigned short*>(&h);
    tlo[r][tx] = bf16bits(f - fh);
  }
  __syncthreads();
  for (int r = ty; r < 32; r += 8) {
    OutHi[(size_t)(bn + r)*R + bk + tx] = thi[tx][r];
    OutLo[(size_t)(bn + r)*R + bk + tx] = tlo[tx][r];
  }
}

// ---------------- kcolmax 2-stage (validated r12; bit-identical scales) ----------------
__global__ __launch_bounds__(256) void kcolmax_part(const float* __restrict__ W1,
                                                    float* __restrict__ pmax) {
  int n = blockIdx.x*256 + threadIdx.x;
  int kc = blockIdx.y;
  float m = 0.f;
  #pragma unroll 8
  for (int k = kc*64; k < kc*64 + 64; ++k)
    m = fmaxf(m, fabsf(W1[(size_t)k*Hdim + n]));
  pmax[(size_t)kc*Hdim + n] = m;
}

__global__ __launch_bounds__(256) void kcolmax_fin(const float* __restrict__ pmax,
                                                   float* __restrict__ scales) {
  int n = blockIdx.x*256 + threadIdx.x;
  float m = 0.f;
  #pragma unroll
  for (int i = 0; i < 32; ++i)
    m = fmaxf(m, pmax[(size_t)i*Hdim + n]);
  scales[n] = m * (1.0f/127.0f);
}

// ---------------- ktr_i8: W1T8[n][k] = rint(W1[k][n]/scales[n]) ----------------
__global__ __launch_bounds__(256) void ktr_i8(const float* __restrict__ In,
                                              const float* __restrict__ scales,
                                              signed char* __restrict__ Out) {
  __shared__ signed char tile[32][33];
  int bk = blockIdx.x*32, bn = blockIdx.y*32;
  int tx = threadIdx.x & 31, ty = threadIdx.x >> 5;
  float rs = 1.0f / scales[bn + tx];      // column n = bn+tx
  for (int r = ty; r < 32; r += 8)
    tile[r][tx] = (signed char)(int)rintf(In[(size_t)(bk + r)*Hdim + bn + tx] * rs);
  __syncthreads();
  for (int r = ty; r < 32; r += 8)
    Out[(size_t)(bn + r)*Hdim + bk + tx] = tile[tx][r];
}

// ---------------- K1 fused: ns0 = xhi@whiT + xhi@wloT + xlo@whiT (validated r8) ----------------
#define K1F_NK 32   // K = 1024, BK = 32
__global__ __launch_bounds__(256) void k1_fused(const unsigned short* __restrict__ xhi,
                                                const unsigned short* __restrict__ xlo,
                                                const unsigned short* __restrict__ whiT,
                                                const unsigned short* __restrict__ wloT,
                                                float* __restrict__ NS0) {
  __shared__ short Ah[2][64*32], Al[2][64*32];
  __shared__ short Bh[2][64*32], Bl[2][64*32];
  int tid = threadIdx.x;
  int l = tid & 63, w = tid >> 6;
  int wm = w >> 1, wn = w & 1;
  int lr = l & 15, lg = l >> 4;
  size_t gm = (size_t)blockIdx.x * 64;
  size_t gn = (size_t)blockIdx.y * 64;
  int srow = l >> 2;
  int scol = ((l & 3)*8) ^ (((l >> 2) & 6) << 2);
  const unsigned short* gah = &xhi [(gm + w*16 + srow)*1024 + scol];
  const unsigned short* gal = &xlo [(gm + w*16 + srow)*1024 + scol];
  const unsigned short* gbh = &whiT[(gn + w*16 + srow)*1024 + scol];
  const unsigned short* gbl = &wloT[(gn + w*16 + srow)*1024 + scol];
  int rdswz = (lr & 6) << 2;
  f32x4 acc[2][2] = {};
  GLD16(gah, &Ah[0][w*512]); GLD16(gal, &Al[0][w*512]);
  GLD16(gbh, &Bh[0][w*512]); GLD16(gbl, &Bl[0][w*512]);
  __syncthreads();
  #pragma unroll 2
  for (int t = 0; t < K1F_NK; ++t) {
    int cur = t & 1;
    if (t + 1 < K1F_NK) {
      int nxt = cur ^ 1; size_t ko = (size_t)(t + 1)*32;
      GLD16(gah + ko, &Ah[nxt][w*512]); GLD16(gal + ko, &Al[nxt][w*512]);
      GLD16(gbh + ko, &Bh[nxt][w*512]); GLD16(gbl + ko, &Bl[nxt][w*512]);
    }
    short8 ah[2], al[2], bh[2], bl[2];
    #pragma unroll
    for (int mi = 0; mi < 2; ++mi) {
      int ro = (wm*32 + mi*16 + lr)*32 + (lg*8 ^ rdswz);
      ah[mi] = *reinterpret_cast<const short8*>(&Ah[cur][ro]);
      al[mi] = *reinterpret_cast<const short8*>(&Al[cur][ro]);
    }
    #pragma unroll
    for (int ni = 0; ni < 2; ++ni) {
      int ro = (wn*32 + ni*16 + lr)*32 + (lg*8 ^ rdswz);
      bh[ni] = *reinterpret_cast<const short8*>(&Bh[cur][ro]);
      bl[ni] = *reinterpret_cast<const short8*>(&Bl[cur][ro]);
    }
    #pragma unroll
    for (int mi = 0; mi < 2; ++mi)
      #pragma unroll
      for (int ni = 0; ni < 2; ++ni) {
        acc[mi][ni] = __builtin_amdgcn_mfma_f32_16x16x32_bf16(ah[mi], bh[ni], acc[mi][ni], 0, 0, 0);
        acc[mi][ni] = __builtin_amdgcn_mfma_f32_16x16x32_bf16(ah[mi], bl[ni], acc[mi][ni], 0, 0, 0);
        acc[mi][ni] = __builtin_amdgcn_mfma_f32_16x16x32_bf16(al[mi], bh[ni], acc[mi][ni], 0, 0, 0);
      }
    __syncthreads();
  }
  #pragma unroll
  for (int mi = 0; mi < 2; ++mi)
    #pragma unroll
    for (int ni = 0; ni < 2; ++ni)
      #pragma unroll
      for (int q = 0; q < 4; ++q)
        NS0[(gm + wm*32 + mi*16 + lg*4 + q)*Hdim + gn + wn*32 + ni*16 + lr] = acc[mi][ni][q];
}

// ---------------- K2: layer-0 sim (x4 vectorized); writes mem0, spk, zeros, i8 Z ----------------
__global__ __launch_bounds__(256) void k2_sim(const float* __restrict__ NS0,
                                              float* __restrict__ out,
                                              signed char* __restrict__ Zb) {
  size_t i4 = ((size_t)blockIdx.x*256 + threadIdx.x)*4;
  float4 nsv = *reinterpret_cast<const float4*>(&NS0[i4]);
  float ns[4] = {nsv.x, nsv.y, nsv.z, nsv.w};
  float* mem = out + OUT_MEM;
  float* spk = out + OUT_SPK;
  float4 z4 = {0.f, 0.f, 0.f, 0.f};
  *reinterpret_cast<float4*>(&mem[i4]) = z4;
  *reinterpret_cast<float4*>(&mem[BH + i4]) = z4;
  *reinterpret_cast<float4*>(&spk[i4]) = z4;
  float m[4] = {0.f, 0.f, 0.f, 0.f};
  for (int t = 1; t < Tdim; ++t) {
    float4 mo, zf; uchar4 z8;
    #pragma unroll
    for (int j = 0; j < 4; ++j) {
      m[j] = __fadd_rn(__fmul_rn(0.9f, m[j]), ns[j]);
      bool sp = m[j] > 1.0f;
      if (sp) m[j] = 0.f;
      ((float*)&mo)[j] = m[j];
      ((float*)&zf)[j] = sp ? 1.f : 0.f;
      ((unsigned char*)&z8)[j] = sp ? (unsigned char)1 : (unsigned char)0;  // i8 1/0
    }
    *reinterpret_cast<float4*>(&mem[(size_t)(2*t)*BH + i4]) = mo;
    *reinterpret_cast<float4*>(&spk[(size_t)t*BH + i4]) = zf;
    *reinterpret_cast<uchar4*>(&Zb[(size_t)(t-1)*BH + i4]) = z8;
  }
}

// ---------------- K3: C = (Z @ W1q) * scale_n, i8 MFMA K=64 ----
// 256x128 tile, 8 waves of 64x64 (acc 64 VGPR -> fits 128-cap, no spill slack 64),
// 3-buffer ring (72 KB LDS), ONE barrier + counted vmcnt(3) per K-tile (r3-validated
// structure), 2 blocks/CU (LDS 144KB, VGPR<=128 -> 16 waves/CU): the second block
// hides barrier/load waits. i32 accum exact -> bit-identical output to r12.
#define NKT3 32   // 2048/64

template<int CB>
__global__ __launch_bounds__(512, 4) void k3_gemm(const signed char* __restrict__ A,    // Zb i8 [M3][2048]
                                                  const signed char* __restrict__ BT,   // W1T8 [2048][2048]
                                                  const float* __restrict__ scales,     // [2048] colmax/127
                                                  float* __restrict__ mem1,
                                                  unsigned short* __restrict__ cbuf) {
  __shared__ signed char As[3][256*64];   // 48 KB
  __shared__ signed char Bs[3][128*64];   // 24 KB
  int tid = threadIdx.x;
  int l = tid & 63;
  int w = tid >> 6;                 // wave 0..7
  int wm = w >> 1, wn = w & 1;      // 4M x 2N; per-wave out 64x64
  int lr = l & 15, lg = l >> 4;
  int rxa = (lr >> 1) & 3;          // read-side chunk XOR == (R>>1)&3 (rows = 16k + lr)

  // T1: grid 1584 = 8*198 bijective, ntile fast (16 blocks share one A-panel in L2)
  int lin = blockIdx.x;
  int wg = (lin & 7)*198 + (lin >> 3);
  int mtile = wg >> 4, ntile = wg & 15;
  size_t gm = (size_t)mtile * 256;
  size_t gn = (size_t)ntile * 128;

  // staging: lane l covers row l>>2 of a 16-row stripe, 16B chunk l&3, source pre-XOR (l>>3)&3
  int srow = l >> 2;
  int scol = ((l & 3) ^ ((l >> 3) & 3)) << 4;
  const signed char* gA0 = &A [(gm +       w*16 + srow)*2048 + scol];
  const signed char* gA1 = &A [(gm + 128 + w*16 + srow)*2048 + scol];
  const signed char* gB  = &BT[(gn +       w*16 + srow)*2048 + scol];

  #define K3_ST(kt, buf) do { size_t _ko = (size_t)(kt)*64;  \
      GLD16(gA0 + _ko, &As[buf][w*1024]);                     \
      GLD16(gA1 + _ko, &As[buf][8192 + w*1024]);              \
      GLD16(gB  + _ko, &Bs[buf][w*1024]); } while (0)

  i32x4 acc[4][4] = {};

  // prologue: tiles 0,1 into bufs 0,1 (per-wave 6 loads outstanding)
  K3_ST(0, 0);
  K3_ST(1, 1);

  int bb = 0;
  for (int kt = 0; kt < NKT3; ++kt) {
    // entry: own tile-kt loads are the 3 oldest outstanding; kt+1's 3 stay in flight (T4)
    if (kt == NKT3 - 1) asm volatile("s_waitcnt vmcnt(0)" ::: "memory");
    else                asm volatile("s_waitcnt vmcnt(3)" ::: "memory");
    __builtin_amdgcn_s_barrier();   // now ALL waves' tile-kt stripes are in LDS
    asm volatile("" ::: "memory");

    int b2 = bb + 2; if (b2 >= 3) b2 -= 3;
    if (kt + 2 < NKT3) K3_ST(kt + 2, b2);   // overwrites tile kt-1: fully read before this barrier

    i32x4 af[4], bf[4];
    #pragma unroll
    for (int mi = 0; mi < 4; ++mi)
      af[mi] = *reinterpret_cast<const i32x4*>(
        &As[bb][(wm*64 + mi*16 + lr)*64 + ((lg ^ rxa)<<4)]);
    #pragma unroll
    for (int ni = 0; ni < 4; ++ni)
      bf[ni] = *reinterpret_cast<const i32x4*>(
        &Bs[bb][(wn*64 + ni*16 + lr)*64 + ((lg ^ rxa)<<4)]);
    __builtin_amdgcn_s_setprio(1);
    #pragma unroll
    for (int mi = 0; mi < 4; ++mi)
      #pragma unroll
      for (int ni = 0; ni < 4; ++ni)
        acc[mi][ni] = __builtin_amdgcn_mfma_i32_16x16x64_i8(af[mi], bf[ni], acc[mi][ni], 0, 0, 0);
    __builtin_amdgcn_s_setprio(0);

    ++bb; if (bb >= 3) bb -= 3;
  }
  #undef K3_ST

  // epilogue: dequant by per-column scale; M-tile == C plane t = mtile+1
  float sc[4];
  #pragma unroll
  for (int ni = 0; ni < 4; ++ni)
    sc[ni] = scales[gn + wn*64 + ni*16 + lr];

  if (CB) {
    unsigned short* cp = cbuf + (size_t)mtile*BH + gn;
    #pragma unroll
    for (int mi = 0; mi < 4; ++mi)
      #pragma unroll
      for (int ni = 0; ni < 4; ++ni)
        #pragma unroll
        for (int q = 0; q < 4; ++q) {
          int b   = wm*64 + mi*16 + lg*4 + q;
          int col = wn*64 + ni*16 + lr;
          cp[(size_t)b*Hdim + col] = bf16bits((float)acc[mi][ni][q] * sc[ni]);
        }
  } else {
    float* plane = mem1 + (size_t)(2*mtile + 3)*BH + gn;
    #pragma unroll
    for (int mi = 0; mi < 4; ++mi)
      #pragma unroll
      for (int ni = 0; ni < 4; ++ni)
        #pragma unroll
        for (int q = 0; q < 4; ++q) {
          int b   = wm*64 + mi*16 + lg*4 + q;
          int col = wn*64 + ni*16 + lr;
          plane[(size_t)b*Hdim + col] = (float)acc[mi][ni][q] * sc[ni];
        }
  }
}

// ---------------- K4a: in-place recurrence over fp32 C planes (x4 vec) ----------------
__global__ __launch_bounds__(256) void k4_rec(float* __restrict__ out) {
  size_t i4 = ((size_t)blockIdx.x*256 + threadIdx.x)*4;
  float* mem = out + OUT_MEM;
  float s[4] = {0.f,0.f,0.f,0.f}, m[4] = {0.f,0.f,0.f,0.f};
  for (int t = 1; t < Tdim; ++t) {
    float4* p = reinterpret_cast<float4*>(&mem[(size_t)(2*t + 1)*BH + i4]);
    float4 c = *p;
    float4 mo;
    #pragma unroll
    for (int j = 0; j < 4; ++j) {
      s[j] = __fadd_rn(__fmul_rn(0.95f, s[j]), ((float*)&c)[j]);
      m[j] = __fadd_rn(__fmul_rn(0.9f, m[j]), s[j]);
      ((float*)&mo)[j] = m[j];
    }
    *p = mo;
  }
  float4 o = {m[0], m[1], m[2], m[3]};
  *reinterpret_cast<float4*>(&out[i4]) = o;
}

// ---------------- K4b: recurrence reading bf16 cbuf (x4 vec) ----------------
__global__ __launch_bounds__(256) void k4_rec_cb(const unsigned short* __restrict__ C,
                                                 float* __restrict__ out) {
  size_t i4 = ((size_t)blockIdx.x*256 + threadIdx.x)*4;
  float* mem = out + OUT_MEM;
  float s[4] = {0.f,0.f,0.f,0.f}, m[4] = {0.f,0.f,0.f,0.f};
  for (int t = 1; t < Tdim; ++t) {
    ushort4 cv = *reinterpret_cast<const ushort4*>(&C[(size_t)(t-1)*BH + i4]);
    float4 mo;
    #pragma unroll
    for (int j = 0; j < 4; ++j) {
      unsigned int u = ((unsigned short*)&cv)[j];
      float c = __uint_as_float(u << 16);
      s[j] = __fadd_rn(__fmul_rn(0.95f, s[j]), c);
      m[j] = __fadd_rn(__fmul_rn(0.9f, m[j]), s[j]);
      ((float*)&mo)[j] = m[j];
    }
    *reinterpret_cast<float4*>(&mem[(size_t)(2*t + 1)*BH + i4]) = mo;
  }
  float4 o = {m[0], m[1], m[2], m[3]};
  *reinterpret_cast<float4*>(&out[i4]) = o;
}

extern "C" void kernel_launch(void* const* d_in, const int* in_sizes, int n_in,
                              void* d_out, int out_size, void* d_ws, size_t ws_size,
                              hipStream_t stream) {
  const float* X  = (const float*)d_in[0];
  const float* W0 = (const float*)d_in[1];
  const float* W1 = (const float*)d_in[2];
  float* out = (float*)d_out;
  char* ws = (char*)d_ws;

  float*          ns0    = (float*)ws;                                  // 2 MiB @0
  signed char*    w1t8   = (signed char*)(ws + (2ull << 20));           // 4 MiB @2M
  float*          scales = (float*)(ws + (6ull << 20));                 // 8 KiB @6M
  float*          pmax   = (float*)(ws + (6ull << 20) + (64ull << 10)); // 256 KiB @6M+64K
  signed char*    zb     = (signed char*)(ws + (10ull << 20));          // 52 MiB @10M
  unsigned short* cbuf   = (unsigned short*)(ws + (10ull << 20) + ZB8); // 99 MiB, optional
  size_t needCb = (10ull << 20) + ZB8 + (size_t)M3*Hdim*2;
  int useCb = (ws_size >= needCb) ? 1 : 0;
  // hi/lo split inputs overlay the zb region; consumed by k1 before k2 writes Zb
  unsigned short* xhi = (unsigned short*)(ws + (10ull << 20));              // 0.5 MiB
  unsigned short* xlo = (unsigned short*)(ws + (10ull << 20) + (512<<10));  // 0.5 MiB
  unsigned short* whi = (unsigned short*)(ws + (11ull << 20));              // 4 MiB
  unsigned short* wlo = (unsigned short*)(ws + (15ull << 20));              // 4 MiB

  kcvt_split  <<<dim3(256),     256, 0, stream>>>(X, xhi, xlo);
  ktr_split   <<<dim3(32, 64),  256, 0, stream>>>(W0, whi, wlo, 1024, 2048); // W0T hi/lo
  kcolmax_part<<<dim3(8, 32),   256, 0, stream>>>(W1, pmax);
  kcolmax_fin <<<dim3(8),       256, 0, stream>>>(pmax, scales);
  ktr_i8      <<<dim3(64, 64),  256, 0, stream>>>(W1, scales, w1t8);         // W1T8 per-col i8
  k1_fused    <<<dim3(4, 32),   256, 0, stream>>>(xhi, xlo, whi, wlo, ns0);
  k2_sim      <<<dim3(BH/1024), 256, 0, stream>>>(ns0, out, zb);
  if (useCb) {
    k3_gemm<1><<<dim3((M3/256)*(Hdim/128)), 512, 0, stream>>>(zb, w1t8, scales, out + OUT_MEM, cbuf);
    k4_rec_cb<<<dim3(BH/1024), 256, 0, stream>>>(cbuf, out);
  } else {
    k3_gemm<0><<<dim3((M3/256)*(Hdim/128)), 512, 0, stream>>>(zb, w1t8, scales, out + OUT_MEM, cbuf);
    k4_rec  <<<dim3(BH/1024), 256, 0, stream>>>(out);
  }
}